// Round 1
// 232.138 us; speedup vs baseline: 1.0422x; 1.0422x over previous
//
#include <hip/hip_runtime.h>

#define TB 512
#define TF 1280
#define TH 2560
#define TK 8
#define TE 9

typedef unsigned short ushortT;
typedef unsigned long long u64;
typedef __attribute__((ext_vector_type(8))) short short8;
typedef __attribute__((ext_vector_type(4))) short short4v;
typedef __attribute__((ext_vector_type(4))) float floatx4;

__device__ __forceinline__ unsigned short f2bf(float f) {
  union { float f; unsigned u; } v; v.f = f;
  unsigned r = v.u + 0x7fffu + ((v.u >> 16) & 1u);   // RNE
  return (unsigned short)(r >> 16);
}

// pack two fp32 -> (bf16(a) low, bf16(b) high), RNE, via v_perm
__device__ __forceinline__ unsigned pk2(float a, float b) {
  union { float f; unsigned u; } ua, ub; ua.f = a; ub.f = b;
  unsigned ra = ua.u + 0x7fffu + ((ua.u >> 16) & 1u);
  unsigned rb = ub.u + 0x7fffu + ((ub.u >> 16) & 1u);
  return __builtin_amdgcn_perm(rb, ra, 0x07060302);  // {ra[31:16], rb[31:16]}
}

__device__ __forceinline__ void gl_lds16(const void* g, void* l) {
  __builtin_amdgcn_global_load_lds(
      (const __attribute__((address_space(1))) unsigned*)g,
      (__attribute__((address_space(3))) unsigned*)l, 16, 0, 0);
}

// ---- merged prep: blocks [0,7200) pack W1, blocks [7200,8560) do prepass ----
// pack: W1 fp32 [e][k][n] -> bf16 k-quad [e][k/4][n][4]  (u64 rows)
// prepass: x -> bf16 k-quad [k/4][m][4], W2 -> bf16 transposed [e][n][h]
__global__ __launch_bounds__(256) void prep_all(
    const float* __restrict__ x, const float* __restrict__ W1,
    const float* __restrict__ W2,
    u64* __restrict__ xq, ushortT* __restrict__ W2t, u64* __restrict__ W1p) {
  const int b = blockIdx.x;
  const int t = threadIdx.x;
  if (b < 7200) {
    // ---- pack_w1 body ----
    const int nt = b % 10;
    const int kt = (b / 10) % 80;
    const int e  = b / 800;
    const int tk = t >> 6, tc = t & 63;
    const int k0 = kt * 16 + tk * 4;
    const int n0 = nt * 256 + tc * 4;
    const float* src = W1 + ((long)e * TF + k0) * TH + n0;
    floatx4 v0 = *(const floatx4*)(src);
    floatx4 v1 = *(const floatx4*)(src + TH);
    floatx4 v2 = *(const floatx4*)(src + 2 * TH);
    floatx4 v3 = *(const floatx4*)(src + 3 * TH);
    u64 q[4];
#pragma unroll
    for (int i = 0; i < 4; ++i)
      q[i] = (u64)pk2(v0[i], v1[i]) | ((u64)pk2(v2[i], v3[i]) << 32);
    u64* dst = W1p + ((long)(e * 320 + (k0 >> 2)) * TH + n0);
    *(ulonglong2*)(dst)     = make_ulonglong2(q[0], q[1]);
    *(ulonglong2*)(dst + 2) = make_ulonglong2(q[2], q[3]);
  } else {
    // ---- prepass body ----
    const int i = (b - 7200) * 256 + t;
    if (i < 320 * 512) {                        // 163840 u64 of xq
      const int kq = i >> 9, m = i & 511;
      floatx4 v = *(const floatx4*)(x + (long)m * TF + kq * 4);
      xq[i] = (u64)pk2(v.x, v.y) | ((u64)pk2(v.z, v.w) << 32);
    } else {
      const int o = i - 320 * 512;
      if (o < TE * TK * TH) {                   // 184320 elements of W2t
        const int hcol = o % TH;
        const int rest = o / TH;
        const int n = rest & 7;
        const int e = rest >> 3;
        W2t[(long)(e * TK + n) * TH + hcol] = f2bf(W2[((long)e * TH + hcol) * TK + n]);
      }
    }
  }
}

// ---- standalone prepass (fallback path only) -------------------------------
__global__ __launch_bounds__(256) void prepass(
    const float* __restrict__ x, const float* __restrict__ W2,
    u64* __restrict__ xq, ushortT* __restrict__ W2t) {
  const int i = blockIdx.x * 256 + threadIdx.x;
  if (i < 320 * 512) {
    const int kq = i >> 9, m = i & 511;
    floatx4 v = *(const floatx4*)(x + (long)m * TF + kq * 4);
    xq[i] = (u64)pk2(v.x, v.y) | ((u64)pk2(v.z, v.w) << 32);
  } else {
    const int o = i - 320 * 512;
    if (o < TE * TK * TH) {
      const int hcol = o % TH;
      const int rest = o / TH;
      const int n = rest & 7;
      const int e = rest >> 3;
      W2t[(long)(e * TK + n) * TH + hcol] = f2bf(W2[((long)e * TH + hcol) * TK + n]);
    }
  }
}

// ---- gemm1: h = relu(x @ W1 + b1), bf16 out. m97 structure.
// BM=128 BN=128 BK=32; 256 thr = 4 waves (2x2), 4x4 frags of 16x16x32.
// XCD-chunked swizzle (720 = 8*90, bijective): 4 m-siblings sharing a W1p slab
// land on the SAME XCD's L2 instead of round-robining across 4 XCDs.
__global__ __launch_bounds__(256) void gemm1_relu(
    const u64* __restrict__ xq, const u64* __restrict__ W1p,
    const float* __restrict__ b1, ushortT* __restrict__ h) {
  __shared__ __align__(16) u64 Aq[8 * 132];   // [kq][m], 8448 B
  __shared__ __align__(16) u64 Bq[8 * 132];   // [kq][n], 8448 B
  const int t = threadIdx.x;
  const int lane = t & 63, w = t >> 6;
  const int bid0 = blockIdx.x;                // hardware: XCD = bid0 & 7
  const int bid = (bid0 & 7) * 90 + (bid0 >> 3);  // contiguous chunk per XCD
  const int mt = bid & 3;                // m-siblings adjacent: W1 slab L2-shared
  const int ctile = bid >> 2;
  const int e = ctile / 20;
  const int hbase = (ctile % 20) * 128;
  const int m0 = mt * 128;
  const int wm = w & 1, wn = w >> 1;
  const int lm = lane & 15, lq = lane >> 4;

  const u64* agB = xq + m0 + lane * 2;                             // + row*512
  const u64* bgB = W1p + ((long)e * 320) * TH + hbase + lane * 2;  // + row*TH

  floatx4 acc[4][4];
#pragma unroll
  for (int i = 0; i < 4; ++i)
#pragma unroll
    for (int j = 0; j < 4; ++j) acc[i][j] = (floatx4){0.f, 0.f, 0.f, 0.f};

  for (int kt = 0; kt < 40; ++kt) {
    const int r0 = kt * 8;
    gl_lds16(agB + (long)(r0 + w) * 512, &Aq[w * 132]);
    gl_lds16(agB + (long)(r0 + w + 4) * 512, &Aq[(w + 4) * 132]);
    gl_lds16(bgB + (long)(r0 + w) * TH, &Bq[w * 132]);
    gl_lds16(bgB + (long)(r0 + w + 4) * TH, &Bq[(w + 4) * 132]);
    __syncthreads();   // drains vmcnt -> tiles visible

    short8 af[4], bf[4];
#pragma unroll
    for (int mg = 0; mg < 4; ++mg) {
      const int m = wm * 64 + mg * 16 + lm;
      ((u64*)&af[mg])[0] = Aq[(2 * lq) * 132 + m];
      ((u64*)&af[mg])[1] = Aq[(2 * lq + 1) * 132 + m];
    }
#pragma unroll
    for (int ng = 0; ng < 4; ++ng) {
      const int n = wn * 64 + ng * 16 + lm;
      ((u64*)&bf[ng])[0] = Bq[(2 * lq) * 132 + n];
      ((u64*)&bf[ng])[1] = Bq[(2 * lq + 1) * 132 + n];
    }
#pragma unroll
    for (int mg = 0; mg < 4; ++mg)
#pragma unroll
      for (int ng = 0; ng < 4; ++ng)
        acc[mg][ng] = __builtin_amdgcn_mfma_f32_16x16x32_bf16(af[mg], bf[ng], acc[mg][ng], 0, 0, 0);
    __syncthreads();   // all waves done reading before next overwrite
  }

  // epilogue: C/D layout col=lane&15, row=(lane>>4)*4+reg
#pragma unroll
  for (int mg = 0; mg < 4; ++mg) {
    const int row = m0 + wm * 64 + mg * 16 + lq * 4;
#pragma unroll
    for (int ng = 0; ng < 4; ++ng) {
      const int col = hbase + wn * 64 + ng * 16 + lm;
      const float bias = b1[e * TH + col];
      floatx4 c = acc[mg][ng];
#pragma unroll
      for (int r = 0; r < 4; ++r) {
        float v = c[r] + bias;
        v = v > 0.f ? v : 0.f;
        h[((long)e * TB + row + r) * TH + col] = f2bf(v);
      }
    }
  }
}

// ---- fallback gemm1 (round-1 proven; used only if ws too small) ------------
__global__ __launch_bounds__(256) void gemm1_fb(
    const float* __restrict__ x, const float* __restrict__ W1,
    const float* __restrict__ b1, ushortT* __restrict__ h) {
  __shared__ __align__(16) ushortT As[128 * 40];
  __shared__ __align__(16) ushortT Bs[128 * 40];
  const int t = threadIdx.x;
  const int tileN = blockIdx.x;
  const int e = tileN / 20;
  const int hbase = (tileN % 20) * 128;
  const int m0 = blockIdx.y * 128;
  const int lane = t & 63, w = t >> 6;
  const int wm = w & 1, wn = w >> 1;
  const int lm = lane & 15, lq = lane >> 4;
  const int lk = lq * 8;
  floatx4 acc[4][4];
#pragma unroll
  for (int i = 0; i < 4; ++i)
#pragma unroll
    for (int j = 0; j < 4; ++j) acc[i][j] = (floatx4){0.f, 0.f, 0.f, 0.f};
  const float* wp = W1 + (long)e * TF * TH + hbase;
  const int cA = (t & 7) * 4;
  const int mA = t >> 3;
  const int nB = t & 127;
  const int gB = t >> 7;
  for (int kt = 0; kt < TF / 32; ++kt) {
    const int k0 = kt * 32;
    if (kt) __syncthreads();
#pragma unroll
    for (int i = 0; i < 4; ++i) {
      const int m = mA + 32 * i;
      floatx4 v = *(const floatx4*)(x + (long)(m0 + m) * TF + k0 + cA);
      short4v s; s.x = f2bf(v.x); s.y = f2bf(v.y); s.z = f2bf(v.z); s.w = f2bf(v.w);
      *(short4v*)&As[m * 40 + cA] = s;
    }
    {
      const float* bp = wp + (long)k0 * TH + nB;
#pragma unroll
      for (int q = 0; q < 4; ++q) {
        const int k4 = gB * 16 + q * 4;
        float f0 = bp[(long)(k4 + 0) * TH];
        float f1 = bp[(long)(k4 + 1) * TH];
        float f2 = bp[(long)(k4 + 2) * TH];
        float f3 = bp[(long)(k4 + 3) * TH];
        short4v s; s.x = f2bf(f0); s.y = f2bf(f1); s.z = f2bf(f2); s.w = f2bf(f3);
        *(short4v*)&Bs[nB * 40 + k4] = s;
      }
    }
    __syncthreads();
    short8 af[4], bfr[4];
#pragma unroll
    for (int mg = 0; mg < 4; ++mg)
      af[mg] = *(const short8*)&As[(wm * 64 + mg * 16 + lm) * 40 + lk];
#pragma unroll
    for (int ng = 0; ng < 4; ++ng)
      bfr[ng] = *(const short8*)&Bs[(wn * 64 + ng * 16 + lm) * 40 + lk];
#pragma unroll
    for (int mg = 0; mg < 4; ++mg)
#pragma unroll
      for (int ng = 0; ng < 4; ++ng)
        acc[mg][ng] = __builtin_amdgcn_mfma_f32_16x16x32_bf16(af[mg], bfr[ng], acc[mg][ng], 0, 0, 0);
  }
#pragma unroll
  for (int mg = 0; mg < 4; ++mg) {
    const int row = m0 + wm * 64 + mg * 16 + lq * 4;
#pragma unroll
    for (int ng = 0; ng < 4; ++ng) {
      const int col = hbase + wn * 64 + ng * 16 + lm;
      const float bias = b1[e * TH + col];
      floatx4 c = acc[mg][ng];
#pragma unroll
      for (int r = 0; r < 4; ++r) {
        float v = c[r] + bias;
        v = v > 0.f ? v : 0.f;
        h[((long)e * TB + row + r) * TH + col] = f2bf(v);
      }
    }
  }
}

// ---- gemm2 + softmax: 288 blocks x 8 waves, K-split 8 ways -----------------
// 8 waves/block (vs 4): 9 waves/CU resident instead of 4.5, and the serial
// MFMA dependency chain halves (10 deep instead of 20) -> latency hiding.
__global__ __launch_bounds__(512) void gemm2_softmax(
    const ushortT* __restrict__ h, const ushortT* __restrict__ W2t,
    const float* __restrict__ b2, float* __restrict__ logits_out,
    float* __restrict__ probs) {
  __shared__ float Ls[8][16][8];
  const int t = threadIdx.x;
  const int lane = t & 63, w = t >> 6;      // 8 waves
  const int e = blockIdx.x >> 5;
  const int r0 = (blockIdx.x & 31) * 16;
  const int lm = lane & 15, lq = lane >> 4;

  const ushortT* hp = h + ((long)(e * TB + r0 + lm)) * TH + w * 320 + lq * 8;
  const int bn = lm < 8 ? lm : 7;
  const ushortT* wp = W2t + ((long)(e * TK + bn)) * TH + w * 320 + lq * 8;

  floatx4 acc = (floatx4){0.f, 0.f, 0.f, 0.f};
#pragma unroll
  for (int kt = 0; kt < 10; ++kt) {
    short8 a = *(const short8*)(hp + kt * 32);
    short8 b = *(const short8*)(wp + kt * 32);
    acc = __builtin_amdgcn_mfma_f32_16x16x32_bf16(a, b, acc, 0, 0, 0);
  }
  if (lm < 8) {
#pragma unroll
    for (int r = 0; r < 4; ++r) Ls[w][lq * 4 + r][lm] = acc[r];
  }
  __syncthreads();
  if (w == 0 && lm < 8) {
    const float bias = b2[e * TK + lm];
#pragma unroll
    for (int r = 0; r < 4; ++r) {
      const int row = lq * 4 + r;
      float v = Ls[0][row][lm] + Ls[1][row][lm] + Ls[2][row][lm] + Ls[3][row][lm]
              + Ls[4][row][lm] + Ls[5][row][lm] + Ls[6][row][lm] + Ls[7][row][lm]
              + bias;
      float mx = v;
      mx = fmaxf(mx, __shfl_xor(mx, 1, 64));
      mx = fmaxf(mx, __shfl_xor(mx, 2, 64));
      mx = fmaxf(mx, __shfl_xor(mx, 4, 64));
      float ex = __expf(v - mx);
      float sm = ex;
      sm += __shfl_xor(sm, 1, 64);
      sm += __shfl_xor(sm, 2, 64);
      sm += __shfl_xor(sm, 4, 64);
      const long idx = ((long)e * TB + r0 + row) * TK + lm;
      logits_out[idx] = v;
      probs[idx] = ex / sm;
    }
  }
}

// ---- leaf path products ----------------------------------------------------
__global__ __launch_bounds__(256) void leafk(const float* __restrict__ probs,
                                             float* __restrict__ out) {
  const int idx = blockIdx.x * 256 + threadIdx.x;
  if (idx >= TB * 73) return;
  const int b = idx / 73, c = idx % 73;
  float v;
  if (c == 0) {
    v = 1.0f;
  } else if (c < 9) {
    v = probs[(long)b * TK + (c - 1)];
  } else {
    const int i = (c - 9) >> 3, j = (c - 9) & 7;
    v = probs[(long)b * TK + i] * probs[((long)(1 + i) * TB + b) * TK + j];
  }
  out[idx] = v;
}

extern "C" void kernel_launch(void* const* d_in, const int* in_sizes, int n_in,
                              void* d_out, int out_size, void* d_ws, size_t ws_size,
                              hipStream_t stream) {
  const float* x  = (const float*)d_in[0];
  const float* W1 = (const float*)d_in[1];
  const float* b1 = (const float*)d_in[2];
  const float* W2 = (const float*)d_in[3];
  const float* b2 = (const float*)d_in[4];
  float* out = (float*)d_out;

  // ws layout
  ushortT* h     = (ushortT*)d_ws;                       // 23,592,960 B
  float*   probs = (float*)((char*)d_ws + 23592960);     //    147,456 B
  u64*     xq    = (u64*)((char*)d_ws + 23740416);       //  1,310,720 B
  ushortT* W2t   = (ushortT*)((char*)d_ws + 25051136);   //    368,640 B
  u64*     W1p   = (u64*)((char*)d_ws + 25419776);       // 58,982,400 B
  const size_t NEED = 25419776 + 58982400;               // 84,402,176 B
  float* logits_out = out + TB * 73;

  if (ws_size >= NEED) {
    prep_all<<<8560, 256, 0, stream>>>(x, W1, W2, xq, W2t, W1p);
    gemm1_relu<<<720, 256, 0, stream>>>(xq, W1p, b1, h);
  } else {
    prepass<<<1360, 256, 0, stream>>>(x, W2, xq, W2t);
    gemm1_fb<<<dim3(180, 4), 256, 0, stream>>>(x, W1, b1, h);
  }
  gemm2_softmax<<<TE * 32, 512, 0, stream>>>(h, W2t, b2, logits_out, probs);
  leafk<<<(TB * 73 + 255) / 256, 256, 0, stream>>>(probs, out);
}